// Round 4
// baseline (1281.672 us; speedup 1.0000x reference)
//
#include <hip/hip_runtime.h>
#include <stdint.h>
#include <stddef.h>

#define N_ROWS 262144
#define CCH    256
#define NGRP   4096

typedef short bf16x8 __attribute__((ext_vector_type(8)));
typedef short bf16x4 __attribute__((ext_vector_type(4)));
typedef float f32x4  __attribute__((ext_vector_type(4)));

static __device__ __forceinline__ short f2bf(float f){
  union { float f; unsigned u; } v; v.f = f;
  unsigned u = v.u;
  unsigned r = (u + 0x7FFFu + ((u >> 16) & 1u)) >> 16;   // round-to-nearest-even
  return (short)r;
}

typedef __attribute__((address_space(1))) const unsigned int GU32;
typedef __attribute__((address_space(3))) unsigned int LU32;
static __device__ __forceinline__ void gload_lds16(const void* g, void* l){
  __builtin_amdgcn_global_load_lds((GU32*)g, (LU32*)l, 16, 0, 0);
}

// ---- cast Wf/Wg to bf16; build Wh transpose (wht[k][j] = Wh[j][k]) ----
__global__ __launch_bounds__(256) void k_castw(
    const float* __restrict__ Wf, const float* __restrict__ Wg,
    const float* __restrict__ Wh,
    short* __restrict__ wfb, short* __restrict__ wgb, float* __restrict__ wht)
{
  int e = blockIdx.x * 256 + threadIdx.x;           // 65536 exact
  wfb[e] = f2bf(Wf[e]);
  wgb[e] = f2bf(Wg[e]);
  int k = e >> 8, j = e & 255;
  wht[e] = Wh[j * 256 + k];
}

// ---- histogram of group ids ----
__global__ __launch_bounds__(256) void k_hist(const int* __restrict__ ix, int* __restrict__ counts){
  int i = blockIdx.x * blockDim.x + threadIdx.x;
  int stride = gridDim.x * blockDim.x;
  for (; i < N_ROWS; i += stride) atomicAdd(&counts[ix[i]], 1);
}

// ---- exclusive prefix sum over 4096 counts -> cursor ----
__global__ __launch_bounds__(1024) void k_scan(const int* __restrict__ counts, int* __restrict__ cursor){
  __shared__ int sums[1024];
  int t = threadIdx.x;
  int base = t * 4;
  int c0 = counts[base], c1 = counts[base+1], c2 = counts[base+2], c3 = counts[base+3];
  sums[t] = c0 + c1 + c2 + c3;
  __syncthreads();
  for (int off = 1; off < 1024; off <<= 1){
    int v = (t >= off) ? sums[t - off] : 0;
    __syncthreads();
    sums[t] += v;
    __syncthreads();
  }
  int prev = (t == 0) ? 0 : sums[t - 1];
  cursor[base]   = prev;
  cursor[base+1] = prev + c0;
  cursor[base+2] = prev + c0 + c1;
  cursor[base+3] = prev + c0 + c1 + c2;
}

// ---- counting-sort scatter fused with fp32->bf16 cast of x ----
__global__ __launch_bounds__(256) void k_scatter_cast(
    const int* __restrict__ ix, int* __restrict__ cursor,
    const float* __restrict__ x, short* __restrict__ xb, int* __restrict__ gid)
{
  int wave = threadIdx.x >> 6;
  int lane = threadIdx.x & 63;
  int i = blockIdx.x * 4 + wave;
  int stride = gridDim.x * 4;
  for (; i < N_ROWS; i += stride){
    int g = ix[i];
    int p;
    if (lane == 0) p = atomicAdd(&cursor[g], 1);
    p = __shfl(p, 0);
    f32x4 v = *(const f32x4*)(x + (size_t)i * 256 + lane * 4);
    bf16x4 b;
    #pragma unroll
    for (int j = 0; j < 4; ++j) b[j] = f2bf(v[j]);
    *(bf16x4*)(xb + (size_t)p * 256 + lane * 4) = b;
    if (lane == 0) gid[p] = g;
  }
}

// ---- fused GEMM (fx & gx) + exp + segment reduce, B-stationary persistent ----
// 512 threads (8 waves); block owns 64 output cols of Wf+Wg for full K=256 in
// 64 KiB LDS, staged once. Zero main-loop barriers. Each wave processes its 32
// rows as two sequential 16-row halves (atomic segmented reduce is
// split-tolerant) to keep live regs ~<=100.
//
// Round-3 post-mortem: __launch_bounds__(512,2) REQUESTS 1 block/CU
// (k = w*4/(B/64) = 2*4/8 = 1) — compiler allocated 128+32 regs for that
// residency, occupancy pinned at 23%, and FETCH=517MB showed every block
// fetching xb privately (zero L2 sharing; partners never co-resident).
// Fix: (512,4) -> cap 128 regs total -> 4 waves/SIMD -> 2 blocks/CU ->
// all 512 blocks co-resident -> XCD partners share xb tiles in L2.
// (Round-1 spilled under this cap at ~190 live regs; halved structure is ~90.)
__global__ __launch_bounds__(512, 4) void k_gemm(
    const short* __restrict__ xb,
    const short* __restrict__ wfb, const short* __restrict__ wgb,
    const float* __restrict__ bfp, const float* __restrict__ bgp,
    const int* __restrict__ gid,
    float* __restrict__ numer, float* __restrict__ denom)
{
  __shared__ short bst[64][512];     // frag f = mat*32 + ks*4 + t ; 64 KiB

  const int tid  = threadIdx.x;
  const int wave = tid >> 6;
  const int lane = tid & 63;
  const int l16  = lane & 15;
  const int quad = lane >> 4;

  // XCD co-location: blocks dispatch round-robin over 8 XCDs (p%8). Same-bslot
  // blocks (cg 0..3) = p, p+8, p+16, p+24 -> same XCD L2 -> xb fetched once.
  const int p     = blockIdx.x;        // 512 blocks
  const int xcd   = p & 7;
  const int ixd   = p >> 3;            // 0..63
  const int cg    = ixd & 3;
  const int bslot = xcd * 16 + (ixd >> 2);   // 0..127
  const int j0    = cg * 64;

  // stage B once: this wave stages frags wave*8 .. wave*8+7
  #pragma unroll
  for (int q = 0; q < 8; ++q){
    int f = wave * 8 + q;
    int mat = f >> 5, ks = (f >> 2) & 7, t = f & 3;
    const short* wsrc = mat ? wgb : wfb;
    const short* src = wsrc + (size_t)(j0 + t * 16 + l16) * 256 + ks * 32 + quad * 8;
    gload_lds16(src, &bst[f][0]);
  }
  __syncthreads();   // only barrier in the kernel

  float bfr[4], bgr[4];
  #pragma unroll
  for (int t = 0; t < 4; ++t){
    bfr[t] = bfp[j0 + t * 16 + l16];
    bgr[t] = bgp[j0 + t * 16 + l16];
  }

  for (int tile = bslot; tile < N_ROWS / 256; tile += 128){
    const int row0 = tile * 256 + wave * 32;

    #pragma unroll 1                      // keep the two halves SEQUENTIAL
    for (int rg = 0; rg < 2; ++rg){
      const int r16 = row0 + rg * 16;
      const int gidv = gid[r16 + l16];    // row ids, replicated per quad
      const short* xr = xb + (size_t)(r16 + l16) * 256 + quad * 8;

      f32x4 accF[4], accG[4];
      #pragma unroll
      for (int t = 0; t < 4; ++t){
        accF[t] = (f32x4){0.f,0.f,0.f,0.f};
        accG[t] = (f32x4){0.f,0.f,0.f,0.f};
      }

      #pragma unroll
      for (int kc = 0; kc < 4; ++kc){
        bf16x8 a0 = *(const bf16x8*)(xr + kc * 64);
        bf16x8 a1 = *(const bf16x8*)(xr + kc * 64 + 32);
        __builtin_amdgcn_s_setprio(1);
        #pragma unroll
        for (int ks = 0; ks < 2; ++ks){
          const int kk = kc * 2 + ks;
          const bf16x8 a = ks ? a1 : a0;
          #pragma unroll
          for (int t = 0; t < 4; ++t){
            bf16x8 bF = *(const bf16x8*)&bst[kk * 4 + t][lane * 8];
            accF[t] = __builtin_amdgcn_mfma_f32_16x16x32_bf16(a, bF, accF[t], 0, 0, 0);
            bf16x8 bG = *(const bf16x8*)&bst[32 + kk * 4 + t][lane * 8];
            accG[t] = __builtin_amdgcn_mfma_f32_16x16x32_bf16(a, bG, accG[t], 0, 0, 0);
          }
        }
        __builtin_amdgcn_s_setprio(0);
      }

      // epilogue: bias + clamp + exp, in-register
      #pragma unroll
      for (int t = 0; t < 4; ++t)
        #pragma unroll
        for (int r = 0; r < 4; ++r){
          float g = accG[t][r] + bgr[t];
          g = fminf(fmaxf(g, -50.f), 50.f);
          float e = __expf(g);
          accF[t][r] = (accF[t][r] + bfr[t]) * e;   // f * e
          accG[t][r] = e;                           // e
        }

      // segmented reduction over this half's 16 sorted rows (heads via ballot)
      int gprev = __shfl(gidv, (lane + 63) & 63);
      bool head = (l16 == 0) || (gidv != gprev);
      unsigned long long hb = __ballot(head) & 0xFFFFull;   // bits 0..15
      int start = 0;
      while (start < 16){
        int g = __shfl(gidv, start);
        unsigned long long rest = hb >> (start + 1);
        int end = rest ? (start + 1 + __builtin_ctzll(rest)) : 16;
        #pragma unroll
        for (int t = 0; t < 4; ++t){
          float sF = 0.f, sE = 0.f;
          #pragma unroll
          for (int r = 0; r < 4; ++r){
            int rl = quad * 4 + r;
            bool in = (rl >= start) && (rl < end);
            sF += in ? accF[t][r] : 0.f;
            sE += in ? accG[t][r] : 0.f;
          }
          sF += __shfl_xor(sF, 16); sF += __shfl_xor(sF, 32);
          sE += __shfl_xor(sE, 16); sE += __shfl_xor(sE, 32);
          if (quad == 0){
            atomicAdd(&numer[(size_t)g * 256 + j0 + t * 16 + l16], sF);
            atomicAdd(&denom[(size_t)g * 256 + j0 + t * 16 + l16], sE);
          }
        }
        start = end;
      }
    }
  }
}

// ---- yh[g] = (numer[g]/denom[g]) @ Wh.T + bh ----
__global__ __launch_bounds__(256) void k_yh(
    const float* __restrict__ numer, const float* __restrict__ denom,
    const float* __restrict__ wht, const float* __restrict__ bh,
    float* __restrict__ yh)
{
  __shared__ float ys[16][256];
  int t = threadIdx.x;
  int g0 = blockIdx.x * 16;
  #pragma unroll
  for (int gg = 0; gg < 16; ++gg){
    size_t idx = (size_t)(g0 + gg) * 256 + t;
    float d = denom[idx];
    ys[gg][t] = (d != 0.f) ? (numer[idx] / d) : 0.f;
  }
  __syncthreads();
  float acc[16];
  #pragma unroll
  for (int gg = 0; gg < 16; ++gg) acc[gg] = 0.f;
  for (int k = 0; k < 256; k += 4){
    float w0 = wht[(k+0) * 256 + t];
    float w1 = wht[(k+1) * 256 + t];
    float w2 = wht[(k+2) * 256 + t];
    float w3 = wht[(k+3) * 256 + t];
    #pragma unroll
    for (int gg = 0; gg < 16; ++gg)
      acc[gg] += w0 * ys[gg][k] + w1 * ys[gg][k+1] + w2 * ys[gg][k+2] + w3 * ys[gg][k+3];
  }
  float b = bh[t];
  #pragma unroll
  for (int gg = 0; gg < 16; ++gg) yh[(size_t)(g0 + gg) * 256 + t] = acc[gg] + b;
}

// ---- out[i] = yh[ix[i]] ----
__global__ __launch_bounds__(256) void k_out(const int* __restrict__ ix,
    const float* __restrict__ yh, float* __restrict__ out)
{
  int wave = threadIdx.x >> 6;
  int lane = threadIdx.x & 63;
  int i = blockIdx.x * 4 + wave;
  int stride = gridDim.x * 4;
  for (; i < N_ROWS; i += stride){
    int g = ix[i];
    f32x4 v = *(const f32x4*)(yh + (size_t)g * 256 + lane * 4);
    *(f32x4*)(out + (size_t)i * 256 + lane * 4) = v;
  }
}

extern "C" void kernel_launch(void* const* d_in, const int* in_sizes, int n_in,
                              void* d_out, int out_size, void* d_ws, size_t ws_size,
                              hipStream_t stream)
{
  const float* x  = (const float*)d_in[0];
  const float* Wf = (const float*)d_in[1];
  const float* bf = (const float*)d_in[2];
  const float* Wg = (const float*)d_in[3];
  const float* bg = (const float*)d_in[4];
  const float* Wh = (const float*)d_in[5];
  const float* bh = (const float*)d_in[6];
  const int*   ix = (const int*)d_in[7];
  float* out = (float*)d_out;

  char* ws = (char*)d_ws;
  float* numer  = (float*)(ws + 0);          // 4 MiB
  float* denom  = (float*)(ws + 4194304);    // 4 MiB
  int*   counts = (int*)  (ws + 8388608);    // 16 KiB
  int*   cursor = (int*)  (ws + 8404992);    // 16 KiB
  float* yh     = (float*)(ws + 8421376);    // 4 MiB
  float* wht    = (float*)(ws + 12615680);   // 256 KiB
  short* wfb    = (short*)(ws + 12877824);   // 128 KiB
  short* wgb    = (short*)(ws + 13008896);   // 128 KiB
  int*   gid    = (int*)  (ws + 13139968);   // 1 MiB

  // sorted bf16 x lives in d_out (134 MiB) — dead until k_out overwrites it
  short* xb = (short*)d_out;

  hipMemsetAsync(ws, 0, 8404992, stream);    // numer + denom + counts

  k_castw<<<256, 256, 0, stream>>>(Wf, Wg, Wh, wfb, wgb, wht);
  k_hist<<<512, 256, 0, stream>>>(ix, counts);
  k_scan<<<1, 1024, 0, stream>>>(counts, cursor);
  k_scatter_cast<<<2048, 256, 0, stream>>>(ix, cursor, x, xb, gid);
  k_gemm<<<512, 512, 0, stream>>>(xb, wfb, wgb, bf, bg, gid, numer, denom);
  k_yh<<<256, 256, 0, stream>>>(numer, denom, wht, bh, yh);
  k_out<<<2048, 256, 0, stream>>>(ix, yh, out);
}

// Round 5
// 794.094 us; speedup vs baseline: 1.6140x; 1.6140x over previous
//
#include <hip/hip_runtime.h>
#include <stdint.h>
#include <stddef.h>

#define N_ROWS 262144
#define CCH    256
#define NGRP   4096

typedef short bf16x8 __attribute__((ext_vector_type(8)));
typedef short bf16x4 __attribute__((ext_vector_type(4)));
typedef float f32x4  __attribute__((ext_vector_type(4)));
typedef float f32x16 __attribute__((ext_vector_type(16)));

static __device__ __forceinline__ short f2bf(float f){
  union { float f; unsigned u; } v; v.f = f;
  unsigned u = v.u;
  unsigned r = (u + 0x7FFFu + ((u >> 16) & 1u)) >> 16;   // round-to-nearest-even
  return (short)r;
}

typedef __attribute__((address_space(1))) const unsigned int GU32;
typedef __attribute__((address_space(3))) unsigned int LU32;
static __device__ __forceinline__ void gload_lds16(const void* g, void* l){
  __builtin_amdgcn_global_load_lds((GU32*)g, (LU32*)l, 16, 0, 0);
}

// ---- cast Wf/Wg to bf16; build Wh transpose (wht[k][j] = Wh[j][k]) ----
__global__ __launch_bounds__(256) void k_castw(
    const float* __restrict__ Wf, const float* __restrict__ Wg,
    const float* __restrict__ Wh,
    short* __restrict__ wfb, short* __restrict__ wgb, float* __restrict__ wht)
{
  int e = blockIdx.x * 256 + threadIdx.x;           // 65536 exact
  wfb[e] = f2bf(Wf[e]);
  wgb[e] = f2bf(Wg[e]);
  int k = e >> 8, j = e & 255;
  wht[e] = Wh[j * 256 + k];
}

// ---- histogram of group ids ----
__global__ __launch_bounds__(256) void k_hist(const int* __restrict__ ix, int* __restrict__ counts){
  int i = blockIdx.x * blockDim.x + threadIdx.x;
  int stride = gridDim.x * blockDim.x;
  for (; i < N_ROWS; i += stride) atomicAdd(&counts[ix[i]], 1);
}

// ---- exclusive prefix sum over 4096 counts -> cursor ----
__global__ __launch_bounds__(1024) void k_scan(const int* __restrict__ counts, int* __restrict__ cursor){
  __shared__ int sums[1024];
  int t = threadIdx.x;
  int base = t * 4;
  int c0 = counts[base], c1 = counts[base+1], c2 = counts[base+2], c3 = counts[base+3];
  sums[t] = c0 + c1 + c2 + c3;
  __syncthreads();
  for (int off = 1; off < 1024; off <<= 1){
    int v = (t >= off) ? sums[t - off] : 0;
    __syncthreads();
    sums[t] += v;
    __syncthreads();
  }
  int prev = (t == 0) ? 0 : sums[t - 1];
  cursor[base]   = prev;
  cursor[base+1] = prev + c0;
  cursor[base+2] = prev + c0 + c1;
  cursor[base+3] = prev + c0 + c1 + c2;
}

// ---- counting-sort scatter fused with fp32->bf16 cast of x ----
__global__ __launch_bounds__(256) void k_scatter_cast(
    const int* __restrict__ ix, int* __restrict__ cursor,
    const float* __restrict__ x, short* __restrict__ xb, int* __restrict__ gid)
{
  int wave = threadIdx.x >> 6;
  int lane = threadIdx.x & 63;
  int i = blockIdx.x * 4 + wave;
  int stride = gridDim.x * 4;
  for (; i < N_ROWS; i += stride){
    int g = ix[i];
    int p;
    if (lane == 0) p = atomicAdd(&cursor[g], 1);
    p = __shfl(p, 0);
    f32x4 v = *(const f32x4*)(x + (size_t)i * 256 + lane * 4);
    bf16x4 b;
    #pragma unroll
    for (int j = 0; j < 4; ++j) b[j] = f2bf(v[j]);
    *(bf16x4*)(xb + (size_t)p * 256 + lane * 4) = b;
    if (lane == 0) gid[p] = g;
  }
}

// ---- fused GEMM (fx & gx) + exp + segment reduce, B-stationary persistent ----
// ROUND-5 RESTRUCTURE (post launch-bounds law from r1-r4):
//   * 32x32x16 MFMA: 16B B-frag covers 32K x 32N -> 2x FLOPs per LDS byte;
//     per wave-strip (32 rows): 32 ds_read_b128 + 32 MFMA (was 128 + 128).
//   * 4-wave / 256-thread blocks, 32-col slice (both mats), LDS = 32 KiB ->
//     5 blocks/CU by LDS; acc = 2 x 16 = 32 regs, natural live ~90 regs ->
//     ~5 waves/SIMD. NO occupancy hint: rounds 1/4 proved forcing the 2nd
//     launch_bounds arg makes the compiler pick a 64/64 arch/AGPR split and
//     spill; natural allocation never spilled (r0,r2,r3).
//   * grid 2048 = 8 colgroups x 256 rowslots, XCD-swizzled so the 8 partners
//     of a rowslot are co-resident on one XCD (xb strip hits L2/L3; xb=134MB
//     fits the 256MB Infinity Cache entirely).
// C/D layout (32x32): col = lane&31, row = (reg&3) + 8*(reg>>2) + 4*(lane>>5).
__global__ __launch_bounds__(256) void k_gemm(
    const short* __restrict__ xb,
    const short* __restrict__ wfb, const short* __restrict__ wgb,
    const float* __restrict__ bfp, const float* __restrict__ bgp,
    const int* __restrict__ gid,
    float* __restrict__ numer, float* __restrict__ denom)
{
  __shared__ short bst[32][512];     // frag f = mat*16 + ks ; 32 KiB

  const int tid  = threadIdx.x;
  const int wave = tid >> 6;
  const int lane = tid & 63;
  const int l31  = lane & 31;
  const int hi   = lane >> 5;

  // XCD co-location: p%8 = XCD (dispatch round-robin). Partners of a rowslot
  // (cg 0..7) are p, p+8, ..., p+56 -> same XCD, adjacent dispatch slots.
  const int p     = blockIdx.x;          // 2048 blocks
  const int xcd   = p & 7;
  const int ixd   = p >> 3;              // 0..255
  const int cg    = ixd & 7;             // 8 column groups of 32
  const int bslot = xcd * 32 + (ixd >> 3);   // 0..255
  const int j0    = cg * 32;

  // stage B once: 32 frags, 8 per wave
  #pragma unroll
  for (int q = 0; q < 8; ++q){
    int f = wave * 8 + q;
    int mat = f >> 4, ks = f & 15;
    const short* wsrc = mat ? wgb : wfb;
    const short* src = wsrc + (size_t)(j0 + l31) * 256 + ks * 16 + hi * 8;
    gload_lds16(src, &bst[f][0]);
  }
  __syncthreads();   // only barrier in the kernel

  const float bfv = bfp[j0 + l31];
  const float bgv = bgp[j0 + l31];

  for (int tile = bslot; tile < N_ROWS / 128; tile += 256){
    const int row0 = tile * 128 + wave * 32;
    const int gidv = gid[row0 + l31];
    const short* xr = xb + (size_t)(row0 + l31) * 256 + hi * 8;

    f32x16 accF, accG;
    #pragma unroll
    for (int r = 0; r < 16; ++r){ accF[r] = 0.f; accG[r] = 0.f; }

    #pragma unroll
    for (int ks = 0; ks < 16; ++ks){
      bf16x8 a  = *(const bf16x8*)(xr + ks * 16);          // row=l31, k=hi*8+j
      bf16x8 bF = *(const bf16x8*)&bst[ks][lane * 8];
      bf16x8 bG = *(const bf16x8*)&bst[16 + ks][lane * 8];
      __builtin_amdgcn_s_setprio(1);
      accF = __builtin_amdgcn_mfma_f32_32x32x16_bf16(a, bF, accF, 0, 0, 0);
      accG = __builtin_amdgcn_mfma_f32_32x32x16_bf16(a, bG, accG, 0, 0, 0);
      __builtin_amdgcn_s_setprio(0);
    }

    // epilogue: bias + clamp + exp, in-register
    #pragma unroll
    for (int r = 0; r < 16; ++r){
      float g = accG[r] + bgv;
      g = fminf(fmaxf(g, -50.f), 50.f);
      float e = __expf(g);
      accF[r] = (accF[r] + bfv) * e;   // f * e
      accG[r] = e;                     // e
    }

    // segmented reduction over this wave's 32 sorted rows.
    // acc row(r) = (r&3) + 8*(r>>2) + 4*hi ; col = j0 + l31.
    int gprev = __shfl(gidv, (l31 + 31) & 31);
    bool head = (l31 == 0) || (gidv != gprev);
    unsigned long long hb = __ballot(head) & 0xFFFFFFFFull;   // bits 0..31
    int start = 0;
    while (start < 32){
      int g = __shfl(gidv, start);
      unsigned long long rest = hb >> (start + 1);
      int end = rest ? (start + 1 + __builtin_ctzll(rest)) : 32;
      float sF = 0.f, sE = 0.f;
      #pragma unroll
      for (int r = 0; r < 16; ++r){
        int row = (r & 3) + 8 * (r >> 2) + 4 * hi;
        bool in = (row >= start) && (row < end);
        sF += in ? accF[r] : 0.f;
        sE += in ? accG[r] : 0.f;
      }
      sF += __shfl_xor(sF, 32);
      sE += __shfl_xor(sE, 32);
      if (hi == 0){
        atomicAdd(&numer[(size_t)g * 256 + j0 + l31], sF);
        atomicAdd(&denom[(size_t)g * 256 + j0 + l31], sE);
      }
      start = end;
    }
  }
}

// ---- yh[g] = (numer[g]/denom[g]) @ Wh.T + bh ----
__global__ __launch_bounds__(256) void k_yh(
    const float* __restrict__ numer, const float* __restrict__ denom,
    const float* __restrict__ wht, const float* __restrict__ bh,
    float* __restrict__ yh)
{
  __shared__ float ys[16][256];
  int t = threadIdx.x;
  int g0 = blockIdx.x * 16;
  #pragma unroll
  for (int gg = 0; gg < 16; ++gg){
    size_t idx = (size_t)(g0 + gg) * 256 + t;
    float d = denom[idx];
    ys[gg][t] = (d != 0.f) ? (numer[idx] / d) : 0.f;
  }
  __syncthreads();
  float acc[16];
  #pragma unroll
  for (int gg = 0; gg < 16; ++gg) acc[gg] = 0.f;
  for (int k = 0; k < 256; k += 4){
    float w0 = wht[(k+0) * 256 + t];
    float w1 = wht[(k+1) * 256 + t];
    float w2 = wht[(k+2) * 256 + t];
    float w3 = wht[(k+3) * 256 + t];
    #pragma unroll
    for (int gg = 0; gg < 16; ++gg)
      acc[gg] += w0 * ys[gg][k] + w1 * ys[gg][k+1] + w2 * ys[gg][k+2] + w3 * ys[gg][k+3];
  }
  float b = bh[t];
  #pragma unroll
  for (int gg = 0; gg < 16; ++gg) yh[(size_t)(g0 + gg) * 256 + t] = acc[gg] + b;
}

// ---- out[i] = yh[ix[i]] ----
__global__ __launch_bounds__(256) void k_out(const int* __restrict__ ix,
    const float* __restrict__ yh, float* __restrict__ out)
{
  int wave = threadIdx.x >> 6;
  int lane = threadIdx.x & 63;
  int i = blockIdx.x * 4 + wave;
  int stride = gridDim.x * 4;
  for (; i < N_ROWS; i += stride){
    int g = ix[i];
    f32x4 v = *(const f32x4*)(yh + (size_t)g * 256 + lane * 4);
    *(f32x4*)(out + (size_t)i * 256 + lane * 4) = v;
  }
}

extern "C" void kernel_launch(void* const* d_in, const int* in_sizes, int n_in,
                              void* d_out, int out_size, void* d_ws, size_t ws_size,
                              hipStream_t stream)
{
  const float* x  = (const float*)d_in[0];
  const float* Wf = (const float*)d_in[1];
  const float* bf = (const float*)d_in[2];
  const float* Wg = (const float*)d_in[3];
  const float* bg = (const float*)d_in[4];
  const float* Wh = (const float*)d_in[5];
  const float* bh = (const float*)d_in[6];
  const int*   ix = (const int*)d_in[7];
  float* out = (float*)d_out;

  char* ws = (char*)d_ws;
  float* numer  = (float*)(ws + 0);          // 4 MiB
  float* denom  = (float*)(ws + 4194304);    // 4 MiB
  int*   counts = (int*)  (ws + 8388608);    // 16 KiB
  int*   cursor = (int*)  (ws + 8404992);    // 16 KiB
  float* yh     = (float*)(ws + 8421376);    // 4 MiB
  float* wht    = (float*)(ws + 12615680);   // 256 KiB
  short* wfb    = (short*)(ws + 12877824);   // 128 KiB
  short* wgb    = (short*)(ws + 13008896);   // 128 KiB
  int*   gid    = (int*)  (ws + 13139968);   // 1 MiB

  // sorted bf16 x lives in d_out (134 MiB) — dead until k_out overwrites it
  short* xb = (short*)d_out;

  hipMemsetAsync(ws, 0, 8404992, stream);    // numer + denom + counts

  k_castw<<<256, 256, 0, stream>>>(Wf, Wg, Wh, wfb, wgb, wht);
  k_hist<<<512, 256, 0, stream>>>(ix, counts);
  k_scan<<<1, 1024, 0, stream>>>(counts, cursor);
  k_scatter_cast<<<2048, 256, 0, stream>>>(ix, cursor, x, xb, gid);
  k_gemm<<<2048, 256, 0, stream>>>(xb, wfb, wgb, bf, bg, gid, numer, denom);
  k_yh<<<256, 256, 0, stream>>>(numer, denom, wht, bh, yh);
  k_out<<<2048, 256, 0, stream>>>(ix, yh, out);
}

// Round 6
// 718.063 us; speedup vs baseline: 1.7849x; 1.1059x over previous
//
#include <hip/hip_runtime.h>
#include <stdint.h>
#include <stddef.h>

#define N_ROWS 262144
#define CCH    256
#define NGRP   4096

typedef short bf16x8 __attribute__((ext_vector_type(8)));
typedef short bf16x4 __attribute__((ext_vector_type(4)));
typedef float f32x4  __attribute__((ext_vector_type(4)));
typedef float f32x16 __attribute__((ext_vector_type(16)));

static __device__ __forceinline__ short f2bf(float f){
  union { float f; unsigned u; } v; v.f = f;
  unsigned u = v.u;
  unsigned r = (u + 0x7FFFu + ((u >> 16) & 1u)) >> 16;   // round-to-nearest-even
  return (short)r;
}

typedef __attribute__((address_space(1))) const unsigned int GU32;
typedef __attribute__((address_space(3))) unsigned int LU32;
static __device__ __forceinline__ void gload_lds16(const void* g, void* l){
  __builtin_amdgcn_global_load_lds((GU32*)g, (LU32*)l, 16, 0, 0);
}

// ---- cast Wf/Wg to bf16; build Wh transpose (wht[k][j] = Wh[j][k]) ----
__global__ __launch_bounds__(256) void k_castw(
    const float* __restrict__ Wf, const float* __restrict__ Wg,
    const float* __restrict__ Wh,
    short* __restrict__ wfb, short* __restrict__ wgb, float* __restrict__ wht)
{
  int e = blockIdx.x * 256 + threadIdx.x;           // 65536 exact
  wfb[e] = f2bf(Wf[e]);
  wgb[e] = f2bf(Wg[e]);
  int k = e >> 8, j = e & 255;
  wht[e] = Wh[j * 256 + k];
}

// ---- histogram of group ids ----
__global__ __launch_bounds__(256) void k_hist(const int* __restrict__ ix, int* __restrict__ counts){
  int i = blockIdx.x * blockDim.x + threadIdx.x;
  int stride = gridDim.x * blockDim.x;
  for (; i < N_ROWS; i += stride) atomicAdd(&counts[ix[i]], 1);
}

// ---- exclusive prefix sum over 4096 counts -> cursor ----
__global__ __launch_bounds__(1024) void k_scan(const int* __restrict__ counts, int* __restrict__ cursor){
  __shared__ int sums[1024];
  int t = threadIdx.x;
  int base = t * 4;
  int c0 = counts[base], c1 = counts[base+1], c2 = counts[base+2], c3 = counts[base+3];
  sums[t] = c0 + c1 + c2 + c3;
  __syncthreads();
  for (int off = 1; off < 1024; off <<= 1){
    int v = (t >= off) ? sums[t - off] : 0;
    __syncthreads();
    sums[t] += v;
    __syncthreads();
  }
  int prev = (t == 0) ? 0 : sums[t - 1];
  cursor[base]   = prev;
  cursor[base+1] = prev + c0;
  cursor[base+2] = prev + c0 + c1;
  cursor[base+3] = prev + c0 + c1 + c2;
}

// ---- counting-sort scatter fused with fp32->bf16 cast of x ----
__global__ __launch_bounds__(256) void k_scatter_cast(
    const int* __restrict__ ix, int* __restrict__ cursor,
    const float* __restrict__ x, short* __restrict__ xb, int* __restrict__ gid)
{
  int wave = threadIdx.x >> 6;
  int lane = threadIdx.x & 63;
  int i = blockIdx.x * 4 + wave;
  int stride = gridDim.x * 4;
  for (; i < N_ROWS; i += stride){
    int g = ix[i];
    int p;
    if (lane == 0) p = atomicAdd(&cursor[g], 1);
    p = __shfl(p, 0);
    f32x4 v = *(const f32x4*)(x + (size_t)i * 256 + lane * 4);
    bf16x4 b;
    #pragma unroll
    for (int j = 0; j < 4; ++j) b[j] = f2bf(v[j]);
    *(bf16x4*)(xb + (size_t)p * 256 + lane * 4) = b;
    if (lane == 0) gid[p] = g;
  }
}

// ---- fused GEMM (fx & gx) + exp + segment reduce, B-stationary persistent ----
// Round-5 geometry kept (verified: no spill, xb L3-resident, FETCH 69MB):
// 32x32x16 MFMA, 4-wave/256-thread blocks, 32-col slice, 32 KiB LDS,
// grid 2048 = 8 colgroups x 256 rowslots, XCD-swizzled.
// Round-6 schedule fix (r5 was 73% stall: serial load->MFMA->epilogue chain):
//  * rolling 4-frag A-load groups: group k+1 issues under group k's MFMAs
//  * next tile's gid + A-group0 prefetched before epilogue+reduce (~700 cyc
//    of VALU hides the L2 latency)  [T14]
//  * single-segment fast path in the reduce (avg group=64 rows -> ~50% of
//    32-row windows are one segment): plain sum, no masked selects
//  * setprio cluster-level (2 toggles/tile, was 32)
// No launch_bounds occupancy hint: rounds 1/4 proved forcing it makes the
// compiler split arch/AGPR 64/64 and spill.
__global__ __launch_bounds__(256) void k_gemm(
    const short* __restrict__ xb,
    const short* __restrict__ wfb, const short* __restrict__ wgb,
    const float* __restrict__ bfp, const float* __restrict__ bgp,
    const int* __restrict__ gid,
    float* __restrict__ numer, float* __restrict__ denom)
{
  __shared__ short bst[32][512];     // frag f = mat*16 + ks ; 32 KiB

  const int tid  = threadIdx.x;
  const int wave = tid >> 6;
  const int lane = tid & 63;
  const int l31  = lane & 31;
  const int hi   = lane >> 5;

  const int p     = blockIdx.x;          // 2048 blocks
  const int xcd   = p & 7;
  const int ixd   = p >> 3;              // 0..255
  const int cg    = ixd & 7;             // 8 column groups of 32
  const int bslot = xcd * 32 + (ixd >> 3);   // 0..255
  const int j0    = cg * 32;

  // stage B once: 32 frags, 8 per wave
  #pragma unroll
  for (int q = 0; q < 8; ++q){
    int f = wave * 8 + q;
    int mat = f >> 4, ks = f & 15;
    const short* wsrc = mat ? wgb : wfb;
    const short* src = wsrc + (size_t)(j0 + l31) * 256 + ks * 16 + hi * 8;
    gload_lds16(src, &bst[f][0]);
  }
  __syncthreads();   // only barrier in the kernel

  const float bfv = bfp[j0 + l31];
  const float bgv = bgp[j0 + l31];

#define KSTEP(A, KS) do { \
    bf16x8 bF_ = *(const bf16x8*)&bst[(KS)][lane * 8]; \
    accF = __builtin_amdgcn_mfma_f32_32x32x16_bf16((A), bF_, accF, 0, 0, 0); \
    bf16x8 bG_ = *(const bf16x8*)&bst[16 + (KS)][lane * 8]; \
    accG = __builtin_amdgcn_mfma_f32_32x32x16_bf16((A), bG_, accG, 0, 0, 0); \
  } while (0)

  // prologue: tile 0's gid + A group0
  int tile = bslot;
  const short* xr = xb + (size_t)(tile * 128 + wave * 32 + l31) * 256 + hi * 8;
  int gidv = gid[tile * 128 + wave * 32 + l31];
  bf16x8 p0 = *(const bf16x8*)(xr + 0 * 16);
  bf16x8 p1 = *(const bf16x8*)(xr + 1 * 16);
  bf16x8 p2 = *(const bf16x8*)(xr + 2 * 16);
  bf16x8 p3 = *(const bf16x8*)(xr + 3 * 16);

  #pragma unroll 1
  for (int it = 0; it < 8; ++it){
    // clamped next-tile (last iter refetches current tile: cached, harmless,
    // keeps the loop branch-free and registers statically assigned)
    const int tnext = (it < 7) ? tile + 256 : tile;
    const int rown  = tnext * 128 + wave * 32 + l31;
    const short* xrn = xb + (size_t)rown * 256 + hi * 8;

    f32x16 accF, accG;
    #pragma unroll
    for (int r = 0; r < 16; ++r){ accF[r] = 0.f; accG[r] = 0.f; }

    // group1 issue, then consume prefetched group0
    bf16x8 a4 = *(const bf16x8*)(xr + 4 * 16);
    bf16x8 a5 = *(const bf16x8*)(xr + 5 * 16);
    bf16x8 a6 = *(const bf16x8*)(xr + 6 * 16);
    bf16x8 a7 = *(const bf16x8*)(xr + 7 * 16);
    __builtin_amdgcn_s_setprio(1);
    KSTEP(p0, 0); KSTEP(p1, 1); KSTEP(p2, 2); KSTEP(p3, 3);
    bf16x8 a8  = *(const bf16x8*)(xr + 8 * 16);
    bf16x8 a9  = *(const bf16x8*)(xr + 9 * 16);
    bf16x8 a10 = *(const bf16x8*)(xr + 10 * 16);
    bf16x8 a11 = *(const bf16x8*)(xr + 11 * 16);
    KSTEP(a4, 4); KSTEP(a5, 5); KSTEP(a6, 6); KSTEP(a7, 7);
    bf16x8 a12 = *(const bf16x8*)(xr + 12 * 16);
    bf16x8 a13 = *(const bf16x8*)(xr + 13 * 16);
    bf16x8 a14 = *(const bf16x8*)(xr + 14 * 16);
    bf16x8 a15 = *(const bf16x8*)(xr + 15 * 16);
    KSTEP(a8, 8); KSTEP(a9, 9); KSTEP(a10, 10); KSTEP(a11, 11);
    // prefetch next tile's gid + A group0 (hidden under epilogue+reduce)
    int gidn = gid[rown];
    bf16x8 n0 = *(const bf16x8*)(xrn + 0 * 16);
    bf16x8 n1 = *(const bf16x8*)(xrn + 1 * 16);
    bf16x8 n2 = *(const bf16x8*)(xrn + 2 * 16);
    bf16x8 n3 = *(const bf16x8*)(xrn + 3 * 16);
    KSTEP(a12, 12); KSTEP(a13, 13); KSTEP(a14, 14); KSTEP(a15, 15);
    __builtin_amdgcn_s_setprio(0);

    // epilogue: bias + clamp + exp, in-register
    #pragma unroll
    for (int r = 0; r < 16; ++r){
      float g = accG[r] + bgv;
      g = fminf(fmaxf(g, -50.f), 50.f);
      float e = __expf(g);
      accF[r] = (accF[r] + bfv) * e;   // f * e
      accG[r] = e;                     // e
    }

    // segmented reduction over this wave's 32 sorted rows.
    // acc row(r) = (r&3) + 8*(r>>2) + 4*hi ; col = j0 + l31.
    int gprev = __shfl(gidv, (l31 + 31) & 31);
    bool head = (l31 == 0) || (gidv != gprev);
    unsigned long long hb = __ballot(head) & 0xFFFFFFFFull;   // bits 0..31
    if (hb == 1ull){
      // fast path: whole 32-row window is one segment — plain sum
      int g = __shfl(gidv, 0);
      float sF = 0.f, sE = 0.f;
      #pragma unroll
      for (int r = 0; r < 16; ++r){ sF += accF[r]; sE += accG[r]; }
      sF += __shfl_xor(sF, 32);
      sE += __shfl_xor(sE, 32);
      if (hi == 0){
        atomicAdd(&numer[(size_t)g * 256 + j0 + l31], sF);
        atomicAdd(&denom[(size_t)g * 256 + j0 + l31], sE);
      }
    } else {
      int start = 0;
      while (start < 32){
        int g = __shfl(gidv, start);
        unsigned long long rest = hb >> (start + 1);
        int end = rest ? (start + 1 + __builtin_ctzll(rest)) : 32;
        float sF = 0.f, sE = 0.f;
        #pragma unroll
        for (int r = 0; r < 16; ++r){
          int row = (r & 3) + 8 * (r >> 2) + 4 * hi;
          bool in = (row >= start) && (row < end);
          sF += in ? accF[r] : 0.f;
          sE += in ? accG[r] : 0.f;
        }
        sF += __shfl_xor(sF, 32);
        sE += __shfl_xor(sE, 32);
        if (hi == 0){
          atomicAdd(&numer[(size_t)g * 256 + j0 + l31], sF);
          atomicAdd(&denom[(size_t)g * 256 + j0 + l31], sE);
        }
        start = end;
      }
    }

    // rotate pipeline registers
    p0 = n0; p1 = n1; p2 = n2; p3 = n3;
    gidv = gidn; xr = xrn; tile = tnext;
  }
#undef KSTEP
}

// ---- yh[g] = (numer[g]/denom[g]) @ Wh.T + bh ----
__global__ __launch_bounds__(256) void k_yh(
    const float* __restrict__ numer, const float* __restrict__ denom,
    const float* __restrict__ wht, const float* __restrict__ bh,
    float* __restrict__ yh)
{
  __shared__ float ys[16][256];
  int t = threadIdx.x;
  int g0 = blockIdx.x * 16;
  #pragma unroll
  for (int gg = 0; gg < 16; ++gg){
    size_t idx = (size_t)(g0 + gg) * 256 + t;
    float d = denom[idx];
    ys[gg][t] = (d != 0.f) ? (numer[idx] / d) : 0.f;
  }
  __syncthreads();
  float acc[16];
  #pragma unroll
  for (int gg = 0; gg < 16; ++gg) acc[gg] = 0.f;
  for (int k = 0; k < 256; k += 4){
    float w0 = wht[(k+0) * 256 + t];
    float w1 = wht[(k+1) * 256 + t];
    float w2 = wht[(k+2) * 256 + t];
    float w3 = wht[(k+3) * 256 + t];
    #pragma unroll
    for (int gg = 0; gg < 16; ++gg)
      acc[gg] += w0 * ys[gg][k] + w1 * ys[gg][k+1] + w2 * ys[gg][k+2] + w3 * ys[gg][k+3];
  }
  float b = bh[t];
  #pragma unroll
  for (int gg = 0; gg < 16; ++gg) yh[(size_t)(g0 + gg) * 256 + t] = acc[gg] + b;
}

// ---- out[i] = yh[ix[i]] ----
__global__ __launch_bounds__(256) void k_out(const int* __restrict__ ix,
    const float* __restrict__ yh, float* __restrict__ out)
{
  int wave = threadIdx.x >> 6;
  int lane = threadIdx.x & 63;
  int i = blockIdx.x * 4 + wave;
  int stride = gridDim.x * 4;
  for (; i < N_ROWS; i += stride){
    int g = ix[i];
    f32x4 v = *(const f32x4*)(yh + (size_t)g * 256 + lane * 4);
    *(f32x4*)(out + (size_t)i * 256 + lane * 4) = v;
  }
}

extern "C" void kernel_launch(void* const* d_in, const int* in_sizes, int n_in,
                              void* d_out, int out_size, void* d_ws, size_t ws_size,
                              hipStream_t stream)
{
  const float* x  = (const float*)d_in[0];
  const float* Wf = (const float*)d_in[1];
  const float* bf = (const float*)d_in[2];
  const float* Wg = (const float*)d_in[3];
  const float* bg = (const float*)d_in[4];
  const float* Wh = (const float*)d_in[5];
  const float* bh = (const float*)d_in[6];
  const int*   ix = (const int*)d_in[7];
  float* out = (float*)d_out;

  char* ws = (char*)d_ws;
  float* numer  = (float*)(ws + 0);          // 4 MiB
  float* denom  = (float*)(ws + 4194304);    // 4 MiB
  int*   counts = (int*)  (ws + 8388608);    // 16 KiB
  int*   cursor = (int*)  (ws + 8404992);    // 16 KiB
  float* yh     = (float*)(ws + 8421376);    // 4 MiB
  float* wht    = (float*)(ws + 12615680);   // 256 KiB
  short* wfb    = (short*)(ws + 12877824);   // 128 KiB
  short* wgb    = (short*)(ws + 13008896);   // 128 KiB
  int*   gid    = (int*)  (ws + 13139968);   // 1 MiB

  // sorted bf16 x lives in d_out (134 MiB) — dead until k_out overwrites it
  short* xb = (short*)d_out;

  hipMemsetAsync(ws, 0, 8404992, stream);    // numer + denom + counts

  k_castw<<<256, 256, 0, stream>>>(Wf, Wg, Wh, wfb, wgb, wht);
  k_hist<<<512, 256, 0, stream>>>(ix, counts);
  k_scan<<<1, 1024, 0, stream>>>(counts, cursor);
  k_scatter_cast<<<2048, 256, 0, stream>>>(ix, cursor, x, xb, gid);
  k_gemm<<<2048, 256, 0, stream>>>(xb, wfb, wgb, bf, bg, gid, numer, denom);
  k_yh<<<256, 256, 0, stream>>>(numer, denom, wht, bh, yh);
  k_out<<<2048, 256, 0, stream>>>(ix, yh, out);
}